// Round 1
// baseline (564.887 us; speedup 1.0000x reference)
//
#include <hip/hip_runtime.h>
#include <math.h>

static constexpr int Bn = 64;
static constexpr int Nn = 64;
static constexpr int Mn = 10;
static constexpr int Dn = 512;
static constexpr int NMn = Nn * Mn;      // 640
static constexpr int ROWS = 8;           // rows (utterances) per block in loss kernel
static constexpr int DCHUNK = 128;       // d-chunk for centroid LDS staging
static constexpr int CPAD = DCHUNK + 1;  // +1 pad -> 2-way bank alias only (free)
static constexpr float EPSV = 1e-12f;

// Kernel 1: normalized full centroids.  c[b,n,:] = normalize(sum_m x[b,n,m,:])
// (normalize(sum) == normalize(mean); norms are ~7 >> eps)
__global__ __launch_bounds__(256) void centroid_k(const float* __restrict__ x,
                                                  float* __restrict__ c) {
  const int bn = blockIdx.x;                       // b*Nn + n
  const float* xp = x + (size_t)bn * Mn * Dn;
  const int tid = threadIdx.x;
  float a0 = 0.f, a1 = 0.f;
#pragma unroll
  for (int m = 0; m < Mn; ++m) {
    a0 += xp[m * Dn + tid];
    a1 += xp[m * Dn + tid + 256];
  }
  float s = a0 * a0 + a1 * a1;
#pragma unroll
  for (int m = 1; m < 64; m <<= 1) s += __shfl_xor(s, m, 64);
  __shared__ float red[4];
  const int wv = tid >> 6, ln = tid & 63;
  if (ln == 0) red[wv] = s;
  __syncthreads();
  const float tot = red[0] + red[1] + red[2] + red[3];
  const float scale = 1.0f / fmaxf(sqrtf(tot), EPSV);
  float* cp = c + (size_t)bn * Dn;
  cp[tid] = a0 * scale;
  cp[tid + 256] = a1 * scale;
}

// Kernel 2: per-row sims + leave-one-out + log-softmax CE, atomic mean.
__global__ __launch_bounds__(256) void loss_k(const float* __restrict__ x,
                                              const float* __restrict__ c,
                                              const float* __restrict__ wp,
                                              const float* __restrict__ bp,
                                              float* __restrict__ out) {
  __shared__ __align__(16) float x_lds[ROWS * Dn];   // 16 KB
  __shared__ float c_lds[Nn * CPAD];                 // 33 KB
  __shared__ float xn2[ROWS];
  __shared__ float sim_lds[ROWS][Nn];                // 2 KB

  const int tid = threadIdx.x;
  const int b = blockIdx.x / (NMn / ROWS);
  const int rblk = blockIdx.x % (NMn / ROWS);
  const int row0 = rblk * ROWS;                      // row index within batch [0,640)
  const float* xrow = x + ((size_t)b * NMn + row0) * Dn;

  // stage 8 x-rows (4096 floats) as float4
  {
    const float4* xs = (const float4*)xrow;
    float4* xd = (float4*)x_lds;
#pragma unroll
    for (int i = tid; i < ROWS * Dn / 4; i += 256) xd[i] = xs[i];
  }
  __syncthreads();

  // per-row squared norms (wave-parallel, 2 rows per wave)
  const int wv = tid >> 6, ln = tid & 63;
  for (int r = wv; r < ROWS; r += 4) {
    float s = 0.f;
#pragma unroll
    for (int j = ln; j < Dn; j += 64) {
      const float v = x_lds[r * Dn + j];
      s += v * v;
    }
#pragma unroll
    for (int m = 1; m < 64; m <<= 1) s += __shfl_xor(s, m, 64);
    if (ln == 0) xn2[r] = s;
  }

  // raw dots r_n = x_row . c_n   (thread t: n = t&63, rows rg*2, rg*2+1)
  const int n = tid & 63;
  const int rg = tid >> 6;
  const int r0 = rg * 2, r1 = rg * 2 + 1;
  float s0 = 0.f, s1 = 0.f;
  const float* cb_base = c + (size_t)b * Nn * Dn;
  for (int cb = 0; cb < Dn; cb += DCHUNK) {
    __syncthreads();  // previous chunk fully consumed
    for (int i = tid; i < Nn * DCHUNK; i += 256) {
      const int nn = i / DCHUNK;
      const int j = i & (DCHUNK - 1);
      c_lds[nn * CPAD + j] = cb_base[(size_t)nn * Dn + cb + j];
    }
    __syncthreads();
#pragma unroll 16
    for (int j = 0; j < DCHUNK; ++j) {
      const float cv = c_lds[n * CPAD + j];
      s0 = fmaf(x_lds[r0 * Dn + cb + j], cv, s0);
      s1 = fmaf(x_lds[r1 * Dn + cb + j], cv, s1);
    }
  }
  sim_lds[r0][n] = s0;
  sim_lds[r1][n] = s1;
  __syncthreads();

  // loss: one wave per row-pair; 64 lanes = 64 logits
  const float W = *wp, Bb = *bp;
  for (int r = wv; r < ROWS; r += 4) {
    const int k = row0 + r;
    const int spk = k / Mn;
    const float rn = sim_lds[r][ln];
    const float x2 = xn2[r];
    const float xn = sqrtf(x2);
    const float inv_xn = 1.0f / fmaxf(xn, EPSV);
    const float rspk = sim_lds[r][spk];   // broadcast
    float sv = rn * inv_xn;
    if (ln == spk) {
      // leave-one-out: e = M*c_spk - x; excl = (x.e)/(|x||e|)
      const float num = (float)Mn * rspk - x2;
      const float en = sqrtf(fmaxf((float)(Mn * Mn) - 2.0f * (float)Mn * rspk + x2, 0.f));
      sv = num / fmaxf(xn * en, EPSV);
    }
    const float logit = W * sv + Bb;
    const float lspk = __shfl(logit, spk, 64);
    float mx = logit;
#pragma unroll
    for (int m = 1; m < 64; m <<= 1) mx = fmaxf(mx, __shfl_xor(mx, m, 64));
    float se = expf(logit - mx);
#pragma unroll
    for (int m = 1; m < 64; m <<= 1) se += __shfl_xor(se, m, 64);
    const float nll = (mx + logf(se)) - lspk;
    if (ln == 0) atomicAdd(out, nll * (1.0f / (float)(Bn * NMn)));
  }
}

extern "C" void kernel_launch(void* const* d_in, const int* in_sizes, int n_in,
                              void* d_out, int out_size, void* d_ws, size_t ws_size,
                              hipStream_t stream) {
  const float* x = (const float*)d_in[0];
  const float* w = (const float*)d_in[1];
  const float* b = (const float*)d_in[2];
  float* out = (float*)d_out;
  float* c = (float*)d_ws;  // Bn*Nn*Dn floats = 8 MB scratch

  hipMemsetAsync(out, 0, sizeof(float), stream);
  hipLaunchKernelGGL(centroid_k, dim3(Bn * Nn), dim3(256), 0, stream, x, c);
  hipLaunchKernelGGL(loss_k, dim3(Bn * (NMn / ROWS)), dim3(256), 0, stream,
                     x, c, w, b, out);
}